// Round 1
// baseline (550.161 us; speedup 1.0000x reference)
//
#include <hip/hip_runtime.h>
#include <hip/hip_bf16.h>

#define D_MODEL 1024
#define NHEADS 16
#define DKH 64
#define BATCH 4
#define SEQ 2048
#define BH_ (BATCH*NHEADS)
#define MROWS (BATCH*SEQ)

typedef __attribute__((ext_vector_type(8))) short bf16x8;
typedef __attribute__((ext_vector_type(4))) float f32x4;
typedef __attribute__((ext_vector_type(4))) short short4v;

static __device__ __forceinline__ unsigned short f2b(float f){
  union { float f; unsigned u; } v; v.f = f;
  unsigned u = v.u;
  return (unsigned short)((u + 0x7FFFu + ((u >> 16) & 1u)) >> 16);
}
static __device__ __forceinline__ float b2f(unsigned short h){
  union { unsigned u; float f; } v; v.u = ((unsigned)h) << 16; return v.f;
}

static __device__ __forceinline__ f32x4 mfma16(bf16x8 a, bf16x8 b, f32x4 c){
  return __builtin_amdgcn_mfma_f32_16x16x32_bf16(a, b, c, 0, 0, 0);
}

// ---------------- fp32 -> bf16 conversion ----------------
__global__ void cvt_bf16_kernel(const float* __restrict__ src,
                                unsigned short* __restrict__ dst, int n4){
  int i = blockIdx.x*blockDim.x + threadIdx.x;
  if (i >= n4) return;
  float4 f = ((const float4*)src)[i];
  short4v o;
  o.x = (short)f2b(f.x); o.y = (short)f2b(f.y);
  o.z = (short)f2b(f.z); o.w = (short)f2b(f.w);
  ((short4v*)dst)[i] = o;
}

// ---------------- NT GEMM: C = A(MxK) * Bw(NxK)^T ----------------
// MODE 0: write bf16 scattered into (B,H,S,dk)  (row=b*S+s, col=h*64+d)
// MODE 1: write fp32 row-major MxN
#define BM 128
#define BN 128
#define BKG 64

template<int MODE>
__global__ __launch_bounds__(256) void gemm_nt(const unsigned short* __restrict__ A,
                                               const unsigned short* __restrict__ Bw,
                                               void* __restrict__ C,
                                               int M, int N, int K)
{
  __shared__ unsigned short As[BM*BKG];
  __shared__ unsigned short Bs[BN*BKG];
  const int t = threadIdx.x;
  const int lane = t & 63;
  const int wv = t >> 6;
  const int wr = wv >> 1, wc = wv & 1;
  const int l15 = lane & 15, l4 = lane >> 4;
  const int m0 = blockIdx.y*BM, n0 = blockIdx.x*BN;

  f32x4 acc[4][4] = {};

  int lrow[4], lsw[4], lke[4];
  #pragma unroll
  for (int i = 0; i < 4; ++i){
    int lin = t*64 + i*16;          // byte position in 16KB tile
    int row = lin >> 7;             // 128 B per row (64 bf16)
    int koff = lin & 127;
    lrow[i] = row;
    lke[i]  = koff >> 1;            // element offset in k
    lsw[i]  = row*128 + (koff ^ ((row & 7) << 4));  // XOR swizzle
  }

  bf16x8 ra[4], rb[4];
  #pragma unroll
  for (int i = 0; i < 4; ++i){
    ra[i] = *(const bf16x8*)(A  + (size_t)(m0 + lrow[i])*K + lke[i]);
    rb[i] = *(const bf16x8*)(Bw + (size_t)(n0 + lrow[i])*K + lke[i]);
  }

  for (int kt = 0; kt < K; kt += BKG){
    if (kt) __syncthreads();
    #pragma unroll
    for (int i = 0; i < 4; ++i){
      *(bf16x8*)((char*)As + lsw[i]) = ra[i];
      *(bf16x8*)((char*)Bs + lsw[i]) = rb[i];
    }
    if (kt + BKG < K){
      #pragma unroll
      for (int i = 0; i < 4; ++i){
        ra[i] = *(const bf16x8*)(A  + (size_t)(m0 + lrow[i])*K + kt + BKG + lke[i]);
        rb[i] = *(const bf16x8*)(Bw + (size_t)(n0 + lrow[i])*K + kt + BKG + lke[i]);
      }
    }
    __syncthreads();
    #pragma unroll
    for (int kk = 0; kk < 2; ++kk){
      bf16x8 af[4], bfr[4];
      #pragma unroll
      for (int mi = 0; mi < 4; ++mi){
        int row = wr*64 + mi*16 + l15;
        int koff = kk*64 + l4*16;
        af[mi] = *(const bf16x8*)((const char*)As + row*128 + (koff ^ ((row & 7) << 4)));
      }
      #pragma unroll
      for (int ni = 0; ni < 4; ++ni){
        int row = wc*64 + ni*16 + l15;
        int koff = kk*64 + l4*16;
        bfr[ni] = *(const bf16x8*)((const char*)Bs + row*128 + (koff ^ ((row & 7) << 4)));
      }
      #pragma unroll
      for (int mi = 0; mi < 4; ++mi)
        #pragma unroll
        for (int ni = 0; ni < 4; ++ni)
          acc[mi][ni] = mfma16(af[mi], bfr[ni], acc[mi][ni]);
    }
  }

  #pragma unroll
  for (int mi = 0; mi < 4; ++mi)
    #pragma unroll
    for (int ni = 0; ni < 4; ++ni)
      #pragma unroll
      for (int r = 0; r < 4; ++r){
        int row = m0 + wr*64 + mi*16 + l4*4 + r;
        int col = n0 + wc*64 + ni*16 + l15;
        float v = acc[mi][ni][r];
        if (MODE == 0){
          int b = row >> 11, s = row & (SEQ-1);
          int h = col >> 6,  d = col & (DKH-1);
          ((unsigned short*)C)[((size_t)(b*NHEADS + h)*SEQ + s)*DKH + d] = f2b(v);
        } else {
          ((float*)C)[(size_t)row*N + col] = v;
        }
      }
}

// ---------------- RoPE in-place on (B,H,S,dk) bf16 ----------------
__global__ void rope_kernel(unsigned int* __restrict__ qk,
                            const int* __restrict__ pos, int npairs){
  int i = blockIdx.x*blockDim.x + threadIdx.x;
  if (i >= npairs) return;
  int j = i & (DKH/2 - 1);
  int s = (i >> 5) & (SEQ-1);
  float p = (float)pos[s];
  float fr = expf(-((float)(2*j) * (1.0f/DKH)) * 9.210340371976184f); // theta^(-2j/dk)
  float ang = p * fr;
  float sn, cs;
  sincosf(ang, &sn, &cs);
  unsigned u = qk[i];
  float x1 = b2f((unsigned short)(u & 0xFFFFu));
  float x2 = b2f((unsigned short)(u >> 16));
  float r1 = x1*cs - x2*sn;
  float r2 = x1*sn + x2*cs;
  qk[i] = (unsigned)f2b(r1) | ((unsigned)f2b(r2) << 16);
}

// ---------------- V transpose (BH,S,dk) -> (BH,dk,S) ----------------
__global__ void vtrans_kernel(const unsigned short* __restrict__ vin,
                              unsigned short* __restrict__ vt){
  __shared__ unsigned short tile[64][65];
  int bh = blockIdx.y;
  int s0 = blockIdx.x * 64;
  const unsigned short* src = vin + ((size_t)bh*SEQ + s0)*DKH;
  for (int i = threadIdx.x; i < 64*64; i += 256)
    tile[i >> 6][i & 63] = src[(size_t)(i >> 6)*DKH + (i & 63)];
  __syncthreads();
  unsigned short* dst = vt + (size_t)bh*DKH*SEQ + s0;
  for (int i = threadIdx.x; i < 64*64; i += 256)
    dst[(size_t)(i >> 6)*SEQ + (i & 63)] = tile[i & 63][i >> 6];
}

// ---------------- causal flash attention ----------------
// Q,K: (BH,S,dk) bf16 ; Vt: (BH,dk,S) bf16 ; Ob: (B,S,H*dk) bf16
__global__ __launch_bounds__(64) void attn_kernel(const unsigned short* __restrict__ Q,
                                                  const unsigned short* __restrict__ Kw,
                                                  const unsigned short* __restrict__ Vt,
                                                  unsigned short* __restrict__ Ob)
{
  __shared__ unsigned short P[16*32];
  const int lane = threadIdx.x;
  const int l15 = lane & 15, l4 = lane >> 4;
  const int bh = blockIdx.x >> 7;
  const int qt = blockIdx.x & 127;
  const int q0 = qt * 16;

  const unsigned short* qb = Q + ((size_t)bh*SEQ + q0)*DKH;
  bf16x8 qa0 = *(const bf16x8*)(qb + l15*DKH + l4*8);
  bf16x8 qa1 = *(const bf16x8*)(qb + l15*DKH + 32 + l4*8);

  float m_r[4] = {-1e30f,-1e30f,-1e30f,-1e30f};
  float l_r[4] = {0.f,0.f,0.f,0.f};
  f32x4 oacc[4] = {};

  const int ntiles = (q0 + 16 + 31) >> 5;
  const unsigned short* kbase = Kw + (size_t)bh*SEQ*DKH;
  const unsigned short* vbase = Vt + (size_t)bh*DKH*SEQ;

  for (int tkv = 0; tkv < ntiles; ++tkv){
    const int kv0 = tkv * 32;
    f32x4 sacc[2];
    #pragma unroll
    for (int c = 0; c < 2; ++c){
      const unsigned short* kb = kbase + (size_t)(kv0 + c*16)*DKH;
      bf16x8 k0 = *(const bf16x8*)(kb + l15*DKH + l4*8);
      bf16x8 k1 = *(const bf16x8*)(kb + l15*DKH + 32 + l4*8);
      f32x4 a = {};
      a = mfma16(qa0, k0, a);
      a = mfma16(qa1, k1, a);
      sacc[c] = a;
    }
    float pv0[4], pv1[4];
    #pragma unroll
    for (int r = 0; r < 4; ++r){
      int row = q0 + l4*4 + r;
      float s0 = sacc[0][r] * 0.125f;
      float s1 = sacc[1][r] * 0.125f;
      if (kv0 + l15 > row)      s0 = -1e30f;
      if (kv0 + 16 + l15 > row) s1 = -1e30f;
      float mr = fmaxf(s0, s1);
      #pragma unroll
      for (int off = 1; off < 16; off <<= 1)
        mr = fmaxf(mr, __shfl_xor(mr, off));
      float mn = fmaxf(m_r[r], mr);
      float p0 = __expf(s0 - mn);
      float p1 = __expf(s1 - mn);
      float rs = p0 + p1;
      #pragma unroll
      for (int off = 1; off < 16; off <<= 1)
        rs += __shfl_xor(rs, off);
      float alpha = __expf(m_r[r] - mn);
      m_r[r] = mn;
      l_r[r] = l_r[r]*alpha + rs;
      #pragma unroll
      for (int dc = 0; dc < 4; ++dc) oacc[dc][r] *= alpha;
      pv0[r] = p0; pv1[r] = p1;
    }
    // P (16x32) acc-layout -> LDS (swizzled), then re-read in A-frag layout
    #pragma unroll
    for (int r = 0; r < 4; ++r){
      int row = l4*4 + r;
      int base = row*64;
      int b0 = (l15*2)        ^ ((row & 3) << 4);
      int b1 = (32 + l15*2)   ^ ((row & 3) << 4);
      *(unsigned short*)((char*)P + base + b0) = f2b(pv0[r]);
      *(unsigned short*)((char*)P + base + b1) = f2b(pv1[r]);
    }
    __syncthreads();
    bf16x8 pa = *(const bf16x8*)((const char*)P + l15*64 + ((l4*16) ^ ((l15 & 3) << 4)));
    const unsigned short* vb = vbase + kv0;
    #pragma unroll
    for (int dc = 0; dc < 4; ++dc){
      bf16x8 vvv = *(const bf16x8*)(vb + (size_t)(dc*16 + l15)*SEQ + l4*8);
      oacc[dc] = mfma16(pa, vvv, oacc[dc]);
    }
    __syncthreads();
  }

  const int b = bh >> 4, h = bh & 15;
  #pragma unroll
  for (int r = 0; r < 4; ++r){
    int s = q0 + l4*4 + r;
    float inv = 1.0f / l_r[r];
    unsigned short* orow = Ob + ((size_t)(b*SEQ + s))*D_MODEL + h*DKH;
    #pragma unroll
    for (int dc = 0; dc < 4; ++dc)
      orow[dc*16 + l15] = f2b(oacc[dc][r] * inv);
  }
}

// ---------------- host orchestration ----------------
extern "C" void kernel_launch(void* const* d_in, const int* in_sizes, int n_in,
                              void* d_out, int out_size, void* d_ws, size_t ws_size,
                              hipStream_t stream)
{
  const float* x  = (const float*)d_in[0];
  const float* wq = (const float*)d_in[1];
  const float* wk = (const float*)d_in[2];
  const float* wv = (const float*)d_in[3];
  const float* wo = (const float*)d_in[4];
  const int* tp   = (const int*)d_in[5];
  float* out = (float*)d_out;

  unsigned short* ws = (unsigned short*)d_ws;
  size_t off = 0;
  unsigned short* xb  = ws + off; off += (size_t)MROWS*D_MODEL;
  unsigned short* wqb = ws + off; off += (size_t)D_MODEL*D_MODEL;
  unsigned short* wkb = ws + off; off += (size_t)D_MODEL*D_MODEL;
  unsigned short* wvb = ws + off; off += (size_t)D_MODEL*D_MODEL;
  unsigned short* wob = ws + off; off += (size_t)D_MODEL*D_MODEL;
  unsigned short* qw  = ws + off; off += (size_t)BH_*SEQ*DKH;
  unsigned short* kw  = ws + off; off += (size_t)BH_*SEQ*DKH;
  unsigned short* vtmp= ws + off; off += (size_t)BH_*SEQ*DKH;
  unsigned short* vt  = ws + off; off += (size_t)BH_*SEQ*DKH;
  unsigned short* ao  = vtmp;  // reuse after transpose

  const int NW = D_MODEL*D_MODEL/4;
  cvt_bf16_kernel<<<(MROWS*D_MODEL/4 + 255)/256, 256, 0, stream>>>(x,  xb,  MROWS*D_MODEL/4);
  cvt_bf16_kernel<<<(NW + 255)/256, 256, 0, stream>>>(wq, wqb, NW);
  cvt_bf16_kernel<<<(NW + 255)/256, 256, 0, stream>>>(wk, wkb, NW);
  cvt_bf16_kernel<<<(NW + 255)/256, 256, 0, stream>>>(wv, wvb, NW);
  cvt_bf16_kernel<<<(NW + 255)/256, 256, 0, stream>>>(wo, wob, NW);

  dim3 gg(D_MODEL/BN, MROWS/BM);
  gemm_nt<0><<<gg, 256, 0, stream>>>(xb, wqb, qw,   MROWS, D_MODEL, D_MODEL);
  gemm_nt<0><<<gg, 256, 0, stream>>>(xb, wkb, kw,   MROWS, D_MODEL, D_MODEL);
  gemm_nt<0><<<gg, 256, 0, stream>>>(xb, wvb, vtmp, MROWS, D_MODEL, D_MODEL);

  const int npairs = BH_*SEQ*(DKH/2);
  rope_kernel<<<(npairs + 255)/256, 256, 0, stream>>>((unsigned int*)qw, tp, npairs);
  rope_kernel<<<(npairs + 255)/256, 256, 0, stream>>>((unsigned int*)kw, tp, npairs);

  vtrans_kernel<<<dim3(SEQ/64, BH_), 256, 0, stream>>>(vtmp, vt);

  attn_kernel<<<BH_*(SEQ/16), 64, 0, stream>>>(qw, kw, vt, ao);

  gemm_nt<1><<<gg, 256, 0, stream>>>(ao, wob, out, MROWS, D_MODEL, D_MODEL);
}

// Round 2
// 301.834 us; speedup vs baseline: 1.8227x; 1.8227x over previous
//
#include <hip/hip_runtime.h>
#include <hip/hip_bf16.h>

#define D_MODEL 1024
#define NHEADS 16
#define DKH 64
#define BATCH 4
#define SEQ 2048
#define BH_ (BATCH*NHEADS)
#define MROWS (BATCH*SEQ)

typedef __attribute__((ext_vector_type(8))) short bf16x8;
typedef __attribute__((ext_vector_type(4))) float f32x4;
typedef __attribute__((ext_vector_type(4))) short short4v;

static __device__ __forceinline__ unsigned short f2b(float f){
  union { float f; unsigned u; } v; v.f = f;
  unsigned u = v.u;
  return (unsigned short)((u + 0x7FFFu + ((u >> 16) & 1u)) >> 16);
}
static __device__ __forceinline__ float b2f(unsigned short h){
  union { unsigned u; float f; } v; v.u = ((unsigned)h) << 16; return v.f;
}

static __device__ __forceinline__ f32x4 mfma16(bf16x8 a, bf16x8 b, f32x4 c){
  return __builtin_amdgcn_mfma_f32_16x16x32_bf16(a, b, c, 0, 0, 0);
}

// ---------------- fp32 -> bf16 conversion ----------------
__global__ void cvt_bf16_kernel(const float* __restrict__ src,
                                unsigned short* __restrict__ dst, int n4){
  int i = blockIdx.x*blockDim.x + threadIdx.x;
  if (i >= n4) return;
  float4 f = ((const float4*)src)[i];
  short4v o;
  o.x = (short)f2b(f.x); o.y = (short)f2b(f.y);
  o.z = (short)f2b(f.z); o.w = (short)f2b(f.w);
  ((short4v*)dst)[i] = o;
}

// ---------------- NT GEMM: C = A(MxK) * Bw(NxK)^T ----------------
#define BM 128
#define BN 128
#define BKG 64

template<int MODE>
__global__ __launch_bounds__(256) void gemm_nt(const unsigned short* __restrict__ A,
                                               const unsigned short* __restrict__ Bw,
                                               void* __restrict__ C,
                                               int M, int N, int K)
{
  __shared__ unsigned short As[BM*BKG];
  __shared__ unsigned short Bs[BN*BKG];
  const int t = threadIdx.x;
  const int lane = t & 63;
  const int wv = t >> 6;
  const int wr = wv >> 1, wc = wv & 1;
  const int l15 = lane & 15, l4 = lane >> 4;
  const int m0 = blockIdx.y*BM, n0 = blockIdx.x*BN;

  f32x4 acc[4][4] = {};

  int lrow[4], lsw[4], lke[4];
  #pragma unroll
  for (int i = 0; i < 4; ++i){
    int lin = t*64 + i*16;
    int row = lin >> 7;
    int koff = lin & 127;
    lrow[i] = row;
    lke[i]  = koff >> 1;
    lsw[i]  = row*128 + (koff ^ ((row & 7) << 4));
  }

  bf16x8 ra[4], rb[4];
  #pragma unroll
  for (int i = 0; i < 4; ++i){
    ra[i] = *(const bf16x8*)(A  + (size_t)(m0 + lrow[i])*K + lke[i]);
    rb[i] = *(const bf16x8*)(Bw + (size_t)(n0 + lrow[i])*K + lke[i]);
  }

  for (int kt = 0; kt < K; kt += BKG){
    if (kt) __syncthreads();
    #pragma unroll
    for (int i = 0; i < 4; ++i){
      *(bf16x8*)((char*)As + lsw[i]) = ra[i];
      *(bf16x8*)((char*)Bs + lsw[i]) = rb[i];
    }
    if (kt + BKG < K){
      #pragma unroll
      for (int i = 0; i < 4; ++i){
        ra[i] = *(const bf16x8*)(A  + (size_t)(m0 + lrow[i])*K + kt + BKG + lke[i]);
        rb[i] = *(const bf16x8*)(Bw + (size_t)(n0 + lrow[i])*K + kt + BKG + lke[i]);
      }
    }
    __syncthreads();
    #pragma unroll
    for (int kk = 0; kk < 2; ++kk){
      bf16x8 af[4], bfr[4];
      #pragma unroll
      for (int mi = 0; mi < 4; ++mi){
        int row = wr*64 + mi*16 + l15;
        int koff = kk*64 + l4*16;
        af[mi] = *(const bf16x8*)((const char*)As + row*128 + (koff ^ ((row & 7) << 4)));
      }
      #pragma unroll
      for (int ni = 0; ni < 4; ++ni){
        int row = wc*64 + ni*16 + l15;
        int koff = kk*64 + l4*16;
        bfr[ni] = *(const bf16x8*)((const char*)Bs + row*128 + (koff ^ ((row & 7) << 4)));
      }
      #pragma unroll
      for (int mi = 0; mi < 4; ++mi)
        #pragma unroll
        for (int ni = 0; ni < 4; ++ni)
          acc[mi][ni] = mfma16(af[mi], bfr[ni], acc[mi][ni]);
    }
  }

  #pragma unroll
  for (int mi = 0; mi < 4; ++mi)
    #pragma unroll
    for (int ni = 0; ni < 4; ++ni)
      #pragma unroll
      for (int r = 0; r < 4; ++r){
        int row = m0 + wr*64 + mi*16 + l4*4 + r;
        int col = n0 + wc*64 + ni*16 + l15;
        float v = acc[mi][ni][r];
        if (MODE == 0){
          int b = row >> 11, s = row & (SEQ-1);
          int h = col >> 6,  d = col & (DKH-1);
          ((unsigned short*)C)[((size_t)(b*NHEADS + h)*SEQ + s)*DKH + d] = f2b(v);
        } else {
          ((float*)C)[(size_t)row*N + col] = v;
        }
      }
}

// ---------------- RoPE in-place on (B,H,S,dk) bf16 ----------------
__global__ void rope_kernel(unsigned int* __restrict__ qk,
                            const int* __restrict__ pos, int npairs){
  int i = blockIdx.x*blockDim.x + threadIdx.x;
  if (i >= npairs) return;
  int j = i & (DKH/2 - 1);
  int s = (i >> 5) & (SEQ-1);
  float p = (float)pos[s];
  float fr = expf(-((float)(2*j) * (1.0f/DKH)) * 9.210340371976184f);
  float ang = p * fr;
  float sn, cs;
  sincosf(ang, &sn, &cs);
  unsigned u = qk[i];
  float x1 = b2f((unsigned short)(u & 0xFFFFu));
  float x2 = b2f((unsigned short)(u >> 16));
  float r1 = x1*cs - x2*sn;
  float r2 = x1*sn + x2*cs;
  qk[i] = (unsigned)f2b(r1) | ((unsigned)f2b(r2) << 16);
}

// ---------------- V transpose (BH,S,dk) -> (BH,dk,S) ----------------
__global__ void vtrans_kernel(const unsigned short* __restrict__ vin,
                              unsigned short* __restrict__ vt){
  __shared__ unsigned short tile[64][65];
  int bh = blockIdx.y;
  int s0 = blockIdx.x * 64;
  const unsigned short* src = vin + ((size_t)bh*SEQ + s0)*DKH;
  for (int i = threadIdx.x; i < 64*64; i += 256)
    tile[i >> 6][i & 63] = src[(size_t)(i >> 6)*DKH + (i & 63)];
  __syncthreads();
  unsigned short* dst = vt + (size_t)bh*DKH*SEQ + s0;
  for (int i = threadIdx.x; i < 64*64; i += 256)
    dst[(size_t)(i >> 6)*SEQ + (i & 63)] = tile[i & 63][i >> 6];
}

// ---------------- causal flash attention, 4 waves x 32 q-rows ----------------
// Q,K: (BH,S,dk) bf16 ; Vt: (BH,dk,S) bf16 ; Ob: (B,S,H*dk) bf16
// Swapped QK^T (S^T in acc: lane col = q), K/V^T tiles LDS-staged double-buffered.
#define QW 32
#define QB 128
#define KVB 64

__global__ __launch_bounds__(256, 2) void attn_kernel(const unsigned short* __restrict__ Q,
                                                      const unsigned short* __restrict__ Kw,
                                                      const unsigned short* __restrict__ Vt,
                                                      unsigned short* __restrict__ Ob)
{
  __shared__ unsigned short Ks[2][KVB*64];   // pre-swizzled content, [k][d]
  __shared__ unsigned short Vs[2][KVB*64];   // pre-swizzled content, [d][k]
  __shared__ unsigned short Ps[4][QW*KVB];   // per-wave P bounce

  const int t = threadIdx.x;
  const int lane = t & 63;
  const int wv = t >> 6;
  const int l15 = lane & 15, l4 = lane >> 4;

  const int bid = blockIdx.x;
  const int bh = bid & (BH_-1);
  const int qt = (SEQ/QB - 1) - (bid >> 6);      // heavy blocks first
  const int q0 = qt * QB;
  const int qw0 = q0 + wv*QW;

  const unsigned short* kg = Kw + (size_t)bh*SEQ*DKH;
  const unsigned short* vg = Vt + (size_t)bh*DKH*SEQ;
  const unsigned short* qg = Q  + ((size_t)bh*SEQ + qw0)*DKH;

  // Q fragments (B-operand layout: lane holds Q[qi*16+l15][c*32 + l4*8 ..+8])
  bf16x8 qa[2][2];
  #pragma unroll
  for (int qi = 0; qi < 2; ++qi)
    #pragma unroll
    for (int c = 0; c < 2; ++c)
      qa[qi][c] = *(const bf16x8*)(qg + (qi*16 + l15)*DKH + c*32 + l4*8);

  float m_r[2] = {-1e30f, -1e30f};
  float l_r[2] = {0.f, 0.f};
  f32x4 oacc[2][4] = {};

  // staging geometry: thread t covers rows {srow, srow+32}, 16B col slot scb
  const int srow = t >> 3;
  const int scb  = (t & 7) * 16;
  const int sko  = scb ^ ((srow & 7) << 4);   // pre-swizzled source byte offset
  const size_t vstride = (size_t)SEQ * 2;

  const int ntB   = q0/KVB + 2;               // tiles this block stages
  const int twmax = (qw0 + QW - 1) >> 6;      // last tile this wave computes

  bf16x8 kl0, kl1, vl0, vl1;
  // prologue: stage tile 0 into buf 0
  {
    const char* ksrc = (const char*)kg;
    const char* vsrc = (const char*)vg;
    kl0 = *(const bf16x8*)(ksrc + srow*128 + sko);
    kl1 = *(const bf16x8*)(ksrc + (srow+32)*128 + sko);
    vl0 = *(const bf16x8*)(vsrc + (size_t)srow*vstride + sko);
    vl1 = *(const bf16x8*)(vsrc + (size_t)(srow+32)*vstride + sko);
    *(bf16x8*)((char*)Ks[0] + srow*128 + scb)      = kl0;
    *(bf16x8*)((char*)Ks[0] + (srow+32)*128 + scb) = kl1;
    *(bf16x8*)((char*)Vs[0] + srow*128 + scb)      = vl0;
    *(bf16x8*)((char*)Vs[0] + (srow+32)*128 + scb) = vl1;
  }

  for (int tt = 0; tt < ntB; ++tt){
    const int cur = tt & 1;
    __syncthreads();
    const bool pre = (tt + 1 < ntB);
    if (pre){
      const size_t kvoff = (size_t)(tt+1) * KVB;
      const char* ksrc = (const char*)kg + kvoff*128;
      const char* vsrc = (const char*)vg + kvoff*2;
      kl0 = *(const bf16x8*)(ksrc + srow*128 + sko);
      kl1 = *(const bf16x8*)(ksrc + (srow+32)*128 + sko);
      vl0 = *(const bf16x8*)(vsrc + (size_t)srow*vstride + sko);
      vl1 = *(const bf16x8*)(vsrc + (size_t)(srow+32)*vstride + sko);
    }

    if (tt <= twmax){
      const char* kb = (const char*)Ks[cur];
      const char* vb = (const char*)Vs[cur];
      char* pb = (char*)Ps[wv];
      const int sw = (l15 & 7) << 4;

      // QK^T (swapped): sacc[kt][qi] = S^T[kv=kt*16+l4*4+r][q=qi*16+l15]
      f32x4 sacc[4][2];
      #pragma unroll
      for (int kt = 0; kt < 4; ++kt){
        const int krow = kt*16 + l15;
        bf16x8 kf0 = *(const bf16x8*)(kb + krow*128 + ((l4*16) ^ sw));
        bf16x8 kf1 = *(const bf16x8*)(kb + krow*128 + ((64 + l4*16) ^ sw));
        #pragma unroll
        for (int qi = 0; qi < 2; ++qi){
          f32x4 a = {};
          a = mfma16(kf0, qa[qi][0], a);
          a = mfma16(kf1, qa[qi][1], a);
          sacc[kt][qi] = a;
        }
      }

      const int kv0 = tt * KVB;
      #pragma unroll
      for (int qi = 0; qi < 2; ++qi){
        const int qrow = qw0 + qi*16 + l15;
        float p[16];
        float mloc = -1e30f;
        #pragma unroll
        for (int kt = 0; kt < 4; ++kt)
          #pragma unroll
          for (int r = 0; r < 4; ++r){
            int kvg = kv0 + kt*16 + l4*4 + r;
            float x = sacc[kt][qi][r] * 0.125f;
            x = (kvg > qrow) ? -1e30f : x;
            p[kt*4+r] = x;
            mloc = fmaxf(mloc, x);
          }
        mloc = fmaxf(mloc, __shfl_xor(mloc, 16));
        mloc = fmaxf(mloc, __shfl_xor(mloc, 32));
        float mn = fmaxf(m_r[qi], mloc);
        float alpha = __expf(m_r[qi] - mn);
        m_r[qi] = mn;
        float rs = 0.f;
        #pragma unroll
        for (int i = 0; i < 16; ++i){ p[i] = __expf(p[i] - mn); rs += p[i]; }
        rs += __shfl_xor(rs, 16);
        rs += __shfl_xor(rs, 32);
        l_r[qi] = l_r[qi]*alpha + rs;
        // rescale O (acc rows are q = l4*4+r -> broadcast alpha by row)
        float ar[4];
        #pragma unroll
        for (int r = 0; r < 4; ++r) ar[r] = __shfl(alpha, l4*4 + r);
        #pragma unroll
        for (int dt = 0; dt < 4; ++dt)
          #pragma unroll
          for (int r = 0; r < 4; ++r) oacc[qi][dt][r] *= ar[r];
        // pack P -> per-wave LDS (swizzled)
        char* pr = pb + (qi*16 + l15)*128;
        #pragma unroll
        for (int kt = 0; kt < 4; ++kt){
          unsigned u0, u1;
          asm("v_cvt_pk_bf16_f32 %0, %1, %2" : "=v"(u0) : "v"(p[kt*4+0]), "v"(p[kt*4+1]));
          asm("v_cvt_pk_bf16_f32 %0, %1, %2" : "=v"(u1) : "v"(p[kt*4+2]), "v"(p[kt*4+3]));
          unsigned long long uu = (unsigned long long)u0 | ((unsigned long long)u1 << 32);
          *(unsigned long long*)(pr + ((kt*32 + l4*8) ^ sw)) = uu;
        }
      }

      // P fragments (A-operand: lane holds P[qi*16+l15][c*32 + l4*8 ..+8])
      bf16x8 pa[2][2];
      #pragma unroll
      for (int qi = 0; qi < 2; ++qi){
        const char* pr = pb + (qi*16 + l15)*128;
        pa[qi][0] = *(const bf16x8*)(pr + ((l4*16) ^ sw));
        pa[qi][1] = *(const bf16x8*)(pr + ((64 + l4*16) ^ sw));
      }

      // PV: oacc[qi][dt] += P(32xKVB) * V(KVBx64)
      #pragma unroll
      for (int dt = 0; dt < 4; ++dt){
        const int vrow = dt*16 + l15;
        bf16x8 vf0 = *(const bf16x8*)(vb + vrow*128 + ((l4*16) ^ sw));
        bf16x8 vf1 = *(const bf16x8*)(vb + vrow*128 + ((64 + l4*16) ^ sw));
        #pragma unroll
        for (int qi = 0; qi < 2; ++qi){
          oacc[qi][dt] = mfma16(pa[qi][0], vf0, oacc[qi][dt]);
          oacc[qi][dt] = mfma16(pa[qi][1], vf1, oacc[qi][dt]);
        }
      }
    }

    if (pre){
      char* kd = (char*)Ks[cur^1];
      char* vd = (char*)Vs[cur^1];
      *(bf16x8*)(kd + srow*128 + scb)      = kl0;
      *(bf16x8*)(kd + (srow+32)*128 + scb) = kl1;
      *(bf16x8*)(vd + srow*128 + scb)      = vl0;
      *(bf16x8*)(vd + (srow+32)*128 + scb) = vl1;
    }
  }

  // epilogue
  const int b = bh >> 4, h = bh & 15;
  #pragma unroll
  for (int qi = 0; qi < 2; ++qi){
    float inv = 1.0f / l_r[qi];
    float ir[4];
    #pragma unroll
    for (int r = 0; r < 4; ++r) ir[r] = __shfl(inv, l4*4 + r);
    #pragma unroll
    for (int r = 0; r < 4; ++r){
      int q = qw0 + qi*16 + l4*4 + r;
      unsigned short* orow = Ob + ((size_t)(b*SEQ + q))*D_MODEL + h*DKH;
      #pragma unroll
      for (int dt = 0; dt < 4; ++dt)
        orow[dt*16 + l15] = f2b(oacc[qi][dt][r] * inv * 0.f + oacc[qi][dt][r] * ir[r]);
    }
  }
}

// ---------------- host orchestration ----------------
extern "C" void kernel_launch(void* const* d_in, const int* in_sizes, int n_in,
                              void* d_out, int out_size, void* d_ws, size_t ws_size,
                              hipStream_t stream)
{
  const float* x  = (const float*)d_in[0];
  const float* wq = (const float*)d_in[1];
  const float* wk = (const float*)d_in[2];
  const float* wv = (const float*)d_in[3];
  const float* wo = (const float*)d_in[4];
  const int* tp   = (const int*)d_in[5];
  float* out = (float*)d_out;

  unsigned short* ws = (unsigned short*)d_ws;
  size_t off = 0;
  unsigned short* xb  = ws + off; off += (size_t)MROWS*D_MODEL;
  unsigned short* wqb = ws + off; off += (size_t)D_MODEL*D_MODEL;
  unsigned short* wkb = ws + off; off += (size_t)D_MODEL*D_MODEL;
  unsigned short* wvb = ws + off; off += (size_t)D_MODEL*D_MODEL;
  unsigned short* wob = ws + off; off += (size_t)D_MODEL*D_MODEL;
  unsigned short* qw  = ws + off; off += (size_t)BH_*SEQ*DKH;
  unsigned short* kw  = ws + off; off += (size_t)BH_*SEQ*DKH;
  unsigned short* vtmp= ws + off; off += (size_t)BH_*SEQ*DKH;
  unsigned short* vt  = ws + off; off += (size_t)BH_*SEQ*DKH;
  unsigned short* ao  = vtmp;  // reuse after transpose

  const int NW = D_MODEL*D_MODEL/4;
  cvt_bf16_kernel<<<(MROWS*D_MODEL/4 + 255)/256, 256, 0, stream>>>(x,  xb,  MROWS*D_MODEL/4);
  cvt_bf16_kernel<<<(NW + 255)/256, 256, 0, stream>>>(wq, wqb, NW);
  cvt_bf16_kernel<<<(NW + 255)/256, 256, 0, stream>>>(wk, wkb, NW);
  cvt_bf16_kernel<<<(NW + 255)/256, 256, 0, stream>>>(wv, wvb, NW);
  cvt_bf16_kernel<<<(NW + 255)/256, 256, 0, stream>>>(wo, wob, NW);

  dim3 gg(D_MODEL/BN, MROWS/BM);
  gemm_nt<0><<<gg, 256, 0, stream>>>(xb, wqb, qw,   MROWS, D_MODEL, D_MODEL);
  gemm_nt<0><<<gg, 256, 0, stream>>>(xb, wkb, kw,   MROWS, D_MODEL, D_MODEL);
  gemm_nt<0><<<gg, 256, 0, stream>>>(xb, wvb, vtmp, MROWS, D_MODEL, D_MODEL);

  const int npairs = BH_*SEQ*(DKH/2);
  rope_kernel<<<(npairs + 255)/256, 256, 0, stream>>>((unsigned int*)qw, tp, npairs);
  rope_kernel<<<(npairs + 255)/256, 256, 0, stream>>>((unsigned int*)kw, tp, npairs);

  vtrans_kernel<<<dim3(SEQ/64, BH_), 256, 0, stream>>>(vtmp, vt);

  attn_kernel<<<BH_*(SEQ/QB), 256, 0, stream>>>(qw, kw, vt, ao);

  gemm_nt<1><<<gg, 256, 0, stream>>>(ao, wob, out, MROWS, D_MODEL, D_MODEL);
}

// Round 3
// 282.933 us; speedup vs baseline: 1.9445x; 1.0668x over previous
//
#include <hip/hip_runtime.h>
#include <hip/hip_bf16.h>

#define D_MODEL 1024
#define NHEADS 16
#define DKH 64
#define BATCH 4
#define SEQ 2048
#define BH_ (BATCH*NHEADS)
#define MROWS (BATCH*SEQ)

typedef __attribute__((ext_vector_type(8))) short bf16x8;
typedef __attribute__((ext_vector_type(4))) float f32x4;
typedef __attribute__((ext_vector_type(4))) short short4v;

static __device__ __forceinline__ unsigned short f2b(float f){
  union { float f; unsigned u; } v; v.f = f;
  unsigned u = v.u;
  return (unsigned short)((u + 0x7FFFu + ((u >> 16) & 1u)) >> 16);
}
static __device__ __forceinline__ float b2f(unsigned short h){
  union { unsigned u; float f; } v; v.u = ((unsigned)h) << 16; return v.f;
}

static __device__ __forceinline__ f32x4 mfma16(bf16x8 a, bf16x8 b, f32x4 c){
  return __builtin_amdgcn_mfma_f32_16x16x32_bf16(a, b, c, 0, 0, 0);
}

static __device__ __forceinline__ float fexp2(float x){
#if __has_builtin(__builtin_amdgcn_exp2f)
  return __builtin_amdgcn_exp2f(x);
#else
  float r; asm("v_exp_f32 %0, %1" : "=v"(r) : "v"(x)); return r;
#endif
}

static __device__ __forceinline__ void gload_lds16(const unsigned short* g, void* l){
  __builtin_amdgcn_global_load_lds((const __attribute__((address_space(1))) void*)g,
                                   (__attribute__((address_space(3))) void*)l,
                                   16, 0, 0);
}

// ---------------- fp32 -> bf16 conversion (x) ----------------
__global__ void cvt_bf16_kernel(const float* __restrict__ src,
                                unsigned short* __restrict__ dst, int n4){
  int i = blockIdx.x*blockDim.x + threadIdx.x;
  if (i >= n4) return;
  float4 f = ((const float4*)src)[i];
  short4v o;
  o.x = (short)f2b(f.x); o.y = (short)f2b(f.y);
  o.z = (short)f2b(f.z); o.w = (short)f2b(f.w);
  ((short4v*)dst)[i] = o;
}

// ---------------- weight conversion: wq|wk|wv -> wcat, wo -> wob ----------------
__global__ void cvt_w_kernel(const float* __restrict__ wq, const float* __restrict__ wk,
                             const float* __restrict__ wv, const float* __restrict__ wo,
                             unsigned short* __restrict__ wcat, unsigned short* __restrict__ wob){
  int i = blockIdx.x*blockDim.x + threadIdx.x;     // 4 * 262144 float4s
  int seg = i >> 18;
  int j = i & 0x3FFFF;
  const float* s = (seg==0) ? wq : (seg==1) ? wk : (seg==2) ? wv : wo;
  unsigned short* d = (seg < 3) ? (wcat + ((size_t)seg << 20)) : wob;
  float4 f = ((const float4*)s)[j];
  short4v o;
  o.x = (short)f2b(f.x); o.y = (short)f2b(f.y);
  o.z = (short)f2b(f.z); o.w = (short)f2b(f.w);
  ((short4v*)d)[j] = o;
}

// ---------------- NT GEMM, m97-style: global_load_lds staging ----------------
// C = A(MxK) * Bw(NxK)^T
// MODE 0: N=3072 fused QKV -> scatter bf16 into QKV[(which)][(b,h,s,d)]
// MODE 1: fp32 row-major MxN
#define BM 128
#define BN 128
#define BKG 64

template<int MODE>
__global__ __launch_bounds__(256, 3) void gemm_nt(const unsigned short* __restrict__ A,
                                                  const unsigned short* __restrict__ Bw,
                                                  void* __restrict__ C,
                                                  int M, int N, int K)
{
  __shared__ unsigned short As[BM*BKG];
  __shared__ unsigned short Bs[BN*BKG];
  const int t = threadIdx.x;
  const int lane = t & 63;
  const int wv = t >> 6;
  const int wr = wv >> 1, wc = wv & 1;
  const int l15 = lane & 15, l4 = lane >> 4;
  const int m0 = blockIdx.y*BM, n0 = blockIdx.x*BN;

  f32x4 acc[4][4] = {};

  // staging geometry: chunk i (1KB LDS) = rows [i*8, i*8+8); lane covers 16B
  const int srow = lane >> 3;          // 0..7 within chunk
  const int sce  = (lane & 7) * 8;     // element offset in k within row

  for (int kt = 0; kt < K; kt += BKG){
    __syncthreads();                   // previous tile consumed
    #pragma unroll
    for (int jj = 0; jj < 4; ++jj){
      const int i = wv + jj*4;
      const int row = i*8 + srow;
      gload_lds16(A  + (size_t)(m0 + row)*K + kt + sce, (char*)As + i*1024 + lane*16);
      gload_lds16(Bw + (size_t)(n0 + row)*K + kt + sce, (char*)Bs + i*1024 + lane*16);
    }
    __syncthreads();                   // vmcnt(0) drained by compiler before barrier
    #pragma unroll
    for (int kk = 0; kk < 2; ++kk){
      bf16x8 af[4], bfr[4];
      #pragma unroll
      for (int mi = 0; mi < 4; ++mi)
        af[mi] = *(const bf16x8*)((const char*)As + (wr*64 + mi*16 + l15)*128 + kk*64 + l4*16);
      #pragma unroll
      for (int ni = 0; ni < 4; ++ni)
        bfr[ni] = *(const bf16x8*)((const char*)Bs + (wc*64 + ni*16 + l15)*128 + kk*64 + l4*16);
      #pragma unroll
      for (int mi = 0; mi < 4; ++mi)
        #pragma unroll
        for (int ni = 0; ni < 4; ++ni)
          acc[mi][ni] = mfma16(af[mi], bfr[ni], acc[mi][ni]);
    }
  }

  #pragma unroll
  for (int mi = 0; mi < 4; ++mi)
    #pragma unroll
    for (int ni = 0; ni < 4; ++ni)
      #pragma unroll
      for (int r = 0; r < 4; ++r){
        int row = m0 + wr*64 + mi*16 + l4*4 + r;
        int col = n0 + wc*64 + ni*16 + l15;
        float v = acc[mi][ni][r];
        if (MODE == 0){
          int which = col >> 10;
          int cl = col & 1023;
          int b = row >> 11, s = row & (SEQ-1);
          int h = cl >> 6,  d = cl & (DKH-1);
          ((unsigned short*)C)[(size_t)which*((size_t)BH_*SEQ*DKH)
                               + ((size_t)(b*NHEADS + h)*SEQ + s)*DKH + d] = f2b(v);
        } else {
          ((float*)C)[(size_t)row*N + col] = v;
        }
      }
}

// ---------------- RoPE in-place on (B,H,S,dk) bf16 ----------------
__global__ void rope_kernel(unsigned int* __restrict__ qk,
                            const int* __restrict__ pos, int npairs){
  int i = blockIdx.x*blockDim.x + threadIdx.x;
  if (i >= npairs) return;
  int j = i & (DKH/2 - 1);
  int s = (i >> 5) & (SEQ-1);
  float p = (float)pos[s];
  float fr = expf(-((float)(2*j) * (1.0f/DKH)) * 9.210340371976184f);
  float ang = p * fr;
  float sn, cs;
  sincosf(ang, &sn, &cs);
  unsigned u = qk[i];
  float x1 = b2f((unsigned short)(u & 0xFFFFu));
  float x2 = b2f((unsigned short)(u >> 16));
  float r1 = x1*cs - x2*sn;
  float r2 = x1*sn + x2*cs;
  qk[i] = (unsigned)f2b(r1) | ((unsigned)f2b(r2) << 16);
}

// ---------------- V transpose (BH,S,dk) -> (BH,dk,S) ----------------
__global__ void vtrans_kernel(const unsigned short* __restrict__ vin,
                              unsigned short* __restrict__ vt){
  __shared__ unsigned short tile[64][65];
  int bh = blockIdx.y;
  int s0 = blockIdx.x * 64;
  const unsigned short* src = vin + ((size_t)bh*SEQ + s0)*DKH;
  for (int i = threadIdx.x; i < 64*64; i += 256)
    tile[i >> 6][i & 63] = src[(size_t)(i >> 6)*DKH + (i & 63)];
  __syncthreads();
  unsigned short* dst = vt + (size_t)bh*DKH*SEQ + s0;
  for (int i = threadIdx.x; i < 64*64; i += 256)
    dst[(size_t)(i >> 6)*SEQ + (i & 63)] = tile[i & 63][i >> 6];
}

// ---------------- causal flash attention, 4 waves x 32 q-rows ----------------
#define QW 32
#define QB 128
#define KVB 64

__global__ __launch_bounds__(256, 2) void attn_kernel(const unsigned short* __restrict__ Q,
                                                      const unsigned short* __restrict__ Kw,
                                                      const unsigned short* __restrict__ Vt,
                                                      unsigned short* __restrict__ Ob)
{
  __shared__ unsigned short Ks[2][KVB*64];
  __shared__ unsigned short Vs[2][KVB*64];
  __shared__ unsigned short Ps[4][QW*KVB];

  const int t = threadIdx.x;
  const int lane = t & 63;
  const int wv = t >> 6;
  const int l15 = lane & 15, l4 = lane >> 4;

  const int bid = blockIdx.x;
  const int bh = bid & (BH_-1);
  const int qt = (SEQ/QB - 1) - (bid >> 6);
  const int q0 = qt * QB;
  const int qw0 = q0 + wv*QW;

  const unsigned short* kg = Kw + (size_t)bh*SEQ*DKH;
  const unsigned short* vg = Vt + (size_t)bh*DKH*SEQ;
  const unsigned short* qg = Q  + ((size_t)bh*SEQ + qw0)*DKH;

  bf16x8 qa[2][2];
  #pragma unroll
  for (int qi = 0; qi < 2; ++qi)
    #pragma unroll
    for (int c = 0; c < 2; ++c)
      qa[qi][c] = *(const bf16x8*)(qg + (qi*16 + l15)*DKH + c*32 + l4*8);

  // softmax state in log2 domain
  const float KAPPA = 0.125f * 1.4426950408889634f;
  float m_r[2] = {-1e30f, -1e30f};
  float l_r[2] = {0.f, 0.f};
  f32x4 oacc[2][4] = {};

  const int srow = t >> 3;
  const int scb  = (t & 7) * 16;
  const int sko  = scb ^ ((srow & 7) << 4);
  const size_t vstride = (size_t)SEQ * 2;

  const int ntB   = q0/KVB + 2;
  const int twmax = (qw0 + QW - 1) >> 6;

  bf16x8 kl0, kl1, vl0, vl1;
  {
    const char* ksrc = (const char*)kg;
    const char* vsrc = (const char*)vg;
    kl0 = *(const bf16x8*)(ksrc + srow*128 + sko);
    kl1 = *(const bf16x8*)(ksrc + (srow+32)*128 + sko);
    vl0 = *(const bf16x8*)(vsrc + (size_t)srow*vstride + sko);
    vl1 = *(const bf16x8*)(vsrc + (size_t)(srow+32)*vstride + sko);
    *(bf16x8*)((char*)Ks[0] + srow*128 + scb)      = kl0;
    *(bf16x8*)((char*)Ks[0] + (srow+32)*128 + scb) = kl1;
    *(bf16x8*)((char*)Vs[0] + srow*128 + scb)      = vl0;
    *(bf16x8*)((char*)Vs[0] + (srow+32)*128 + scb) = vl1;
  }

  for (int tt = 0; tt < ntB; ++tt){
    const int cur = tt & 1;
    __syncthreads();
    const bool pre = (tt + 1 < ntB);
    if (pre){
      const size_t kvoff = (size_t)(tt+1) * KVB;
      const char* ksrc = (const char*)kg + kvoff*128;
      const char* vsrc = (const char*)vg + kvoff*2;
      kl0 = *(const bf16x8*)(ksrc + srow*128 + sko);
      kl1 = *(const bf16x8*)(ksrc + (srow+32)*128 + sko);
      vl0 = *(const bf16x8*)(vsrc + (size_t)srow*vstride + sko);
      vl1 = *(const bf16x8*)(vsrc + (size_t)(srow+32)*vstride + sko);
    }

    if (tt <= twmax){
      const char* kb = (const char*)Ks[cur];
      const char* vb = (const char*)Vs[cur];
      char* pb = (char*)Ps[wv];
      const int sw = (l15 & 7) << 4;
      const bool needmask = (tt == twmax);

      f32x4 sacc[4][2];
      #pragma unroll
      for (int kt = 0; kt < 4; ++kt){
        const int krow = kt*16 + l15;
        bf16x8 kf0 = *(const bf16x8*)(kb + krow*128 + ((l4*16) ^ sw));
        bf16x8 kf1 = *(const bf16x8*)(kb + krow*128 + ((64 + l4*16) ^ sw));
        #pragma unroll
        for (int qi = 0; qi < 2; ++qi){
          f32x4 a = {};
          a = mfma16(kf0, qa[qi][0], a);
          a = mfma16(kf1, qa[qi][1], a);
          sacc[kt][qi] = a;
        }
      }

      const int kv0 = tt * KVB;
      #pragma unroll
      for (int qi = 0; qi < 2; ++qi){
        const int qrow = qw0 + qi*16 + l15;
        float p[16];
        float mloc = -1e30f;
        #pragma unroll
        for (int kt = 0; kt < 4; ++kt)
          #pragma unroll
          for (int r = 0; r < 4; ++r){
            float x = sacc[kt][qi][r] * KAPPA;
            if (needmask){
              int kvg = kv0 + kt*16 + l4*4 + r;
              x = (kvg > qrow) ? -1e30f : x;
            }
            p[kt*4+r] = x;
            mloc = fmaxf(mloc, x);
          }
        mloc = fmaxf(mloc, __shfl_xor(mloc, 16));
        mloc = fmaxf(mloc, __shfl_xor(mloc, 32));

        const bool skip = __all(mloc - m_r[qi] <= 12.0f);   // defer-max (T13)
        float mn = m_r[qi];
        if (!skip){
          mn = fmaxf(m_r[qi], mloc);
          float alpha = fexp2(m_r[qi] - mn);
          m_r[qi] = mn;
          l_r[qi] *= alpha;
          float ar[4];
          #pragma unroll
          for (int r = 0; r < 4; ++r) ar[r] = __shfl(alpha, l4*4 + r);
          #pragma unroll
          for (int dt = 0; dt < 4; ++dt)
            #pragma unroll
            for (int r = 0; r < 4; ++r) oacc[qi][dt][r] *= ar[r];
        }
        float rs = 0.f;
        #pragma unroll
        for (int i = 0; i < 16; ++i){ p[i] = fexp2(p[i] - mn); rs += p[i]; }
        rs += __shfl_xor(rs, 16);
        rs += __shfl_xor(rs, 32);
        l_r[qi] += rs;

        char* pr = pb + (qi*16 + l15)*128;
        #pragma unroll
        for (int kt = 0; kt < 4; ++kt){
          unsigned u0, u1;
          asm("v_cvt_pk_bf16_f32 %0, %1, %2" : "=v"(u0) : "v"(p[kt*4+0]), "v"(p[kt*4+1]));
          asm("v_cvt_pk_bf16_f32 %0, %1, %2" : "=v"(u1) : "v"(p[kt*4+2]), "v"(p[kt*4+3]));
          unsigned long long uu = (unsigned long long)u0 | ((unsigned long long)u1 << 32);
          *(unsigned long long*)(pr + ((kt*32 + l4*8) ^ sw)) = uu;
        }
      }

      bf16x8 pa[2][2];
      #pragma unroll
      for (int qi = 0; qi < 2; ++qi){
        const char* pr = pb + (qi*16 + l15)*128;
        pa[qi][0] = *(const bf16x8*)(pr + ((l4*16) ^ sw));
        pa[qi][1] = *(const bf16x8*)(pr + ((64 + l4*16) ^ sw));
      }

      #pragma unroll
      for (int dt = 0; dt < 4; ++dt){
        const int vrow = dt*16 + l15;
        bf16x8 vf0 = *(const bf16x8*)(vb + vrow*128 + ((l4*16) ^ sw));
        bf16x8 vf1 = *(const bf16x8*)(vb + vrow*128 + ((64 + l4*16) ^ sw));
        #pragma unroll
        for (int qi = 0; qi < 2; ++qi){
          oacc[qi][dt] = mfma16(pa[qi][0], vf0, oacc[qi][dt]);
          oacc[qi][dt] = mfma16(pa[qi][1], vf1, oacc[qi][dt]);
        }
      }
    }

    if (pre){
      char* kd = (char*)Ks[cur^1];
      char* vd = (char*)Vs[cur^1];
      *(bf16x8*)(kd + srow*128 + scb)      = kl0;
      *(bf16x8*)(kd + (srow+32)*128 + scb) = kl1;
      *(bf16x8*)(vd + srow*128 + scb)      = vl0;
      *(bf16x8*)(vd + (srow+32)*128 + scb) = vl1;
    }
  }

  const int b = bh >> 4, h = bh & 15;
  #pragma unroll
  for (int qi = 0; qi < 2; ++qi){
    float inv = 1.0f / l_r[qi];
    float ir[4];
    #pragma unroll
    for (int r = 0; r < 4; ++r) ir[r] = __shfl(inv, l4*4 + r);
    #pragma unroll
    for (int r = 0; r < 4; ++r){
      int q = qw0 + qi*16 + l4*4 + r;
      unsigned short* orow = Ob + ((size_t)(b*SEQ + q))*D_MODEL + h*DKH;
      #pragma unroll
      for (int dt = 0; dt < 4; ++dt)
        orow[dt*16 + l15] = f2b(oacc[qi][dt][r] * ir[r]);
    }
  }
}

// ---------------- host orchestration ----------------
extern "C" void kernel_launch(void* const* d_in, const int* in_sizes, int n_in,
                              void* d_out, int out_size, void* d_ws, size_t ws_size,
                              hipStream_t stream)
{
  const float* x  = (const float*)d_in[0];
  const float* wq = (const float*)d_in[1];
  const float* wk = (const float*)d_in[2];
  const float* wv = (const float*)d_in[3];
  const float* wo = (const float*)d_in[4];
  const int* tp   = (const int*)d_in[5];
  float* out = (float*)d_out;

  unsigned short* ws = (unsigned short*)d_ws;
  size_t off = 0;
  unsigned short* xb   = ws + off; off += (size_t)MROWS*D_MODEL;
  unsigned short* wcat = ws + off; off += (size_t)3*D_MODEL*D_MODEL;
  unsigned short* wob  = ws + off; off += (size_t)D_MODEL*D_MODEL;
  unsigned short* qw   = ws + off; off += (size_t)BH_*SEQ*DKH;   // QKV contiguous
  unsigned short* kw   = ws + off; off += (size_t)BH_*SEQ*DKH;
  unsigned short* vtmp = ws + off; off += (size_t)BH_*SEQ*DKH;
  unsigned short* vt   = ws + off; off += (size_t)BH_*SEQ*DKH;
  unsigned short* ao   = vtmp;  // reuse after transpose

  cvt_bf16_kernel<<<(MROWS*D_MODEL/4 + 255)/256, 256, 0, stream>>>(x, xb, MROWS*D_MODEL/4);
  cvt_w_kernel<<<(4*262144 + 255)/256, 256, 0, stream>>>(wq, wk, wv, wo, wcat, wob);

  // fused QKV projection: N = 3072
  gemm_nt<0><<<dim3(3*D_MODEL/BN, MROWS/BM), 256, 0, stream>>>(xb, wcat, qw, MROWS, 3*D_MODEL, D_MODEL);

  const int npairs = BH_*SEQ*(DKH/2);
  rope_kernel<<<(npairs + 255)/256, 256, 0, stream>>>((unsigned int*)qw, tp, npairs);
  rope_kernel<<<(npairs + 255)/256, 256, 0, stream>>>((unsigned int*)kw, tp, npairs);

  vtrans_kernel<<<dim3(SEQ/64, BH_), 256, 0, stream>>>(vtmp, vt);

  attn_kernel<<<BH_*(SEQ/QB), 256, 0, stream>>>(qw, kw, vt, ao);

  gemm_nt<1><<<dim3(D_MODEL/BN, MROWS/BM), 256, 0, stream>>>(ao, wob, out, MROWS, D_MODEL, D_MODEL);
}

// Round 6
// 260.513 us; speedup vs baseline: 2.1118x; 1.0861x over previous
//
#include <hip/hip_runtime.h>
#include <hip/hip_bf16.h>

#define D_MODEL 1024
#define NHEADS 16
#define DKH 64
#define BATCH 4
#define SEQ 2048
#define BH_ (BATCH*NHEADS)
#define MROWS (BATCH*SEQ)

typedef __attribute__((ext_vector_type(8))) short bf16x8;
typedef __attribute__((ext_vector_type(4))) float f32x4;
typedef __attribute__((ext_vector_type(4))) short short4v;

static __device__ __forceinline__ unsigned short f2b(float f){
  union { float f; unsigned u; } v; v.f = f;
  unsigned u = v.u;
  return (unsigned short)((u + 0x7FFFu + ((u >> 16) & 1u)) >> 16);
}
static __device__ __forceinline__ float b2f(unsigned short h){
  union { unsigned u; float f; } v; v.u = ((unsigned)h) << 16; return v.f;
}

static __device__ __forceinline__ f32x4 mfma16(bf16x8 a, bf16x8 b, f32x4 c){
  return __builtin_amdgcn_mfma_f32_16x16x32_bf16(a, b, c, 0, 0, 0);
}

static __device__ __forceinline__ float fexp2(float x){
#if __has_builtin(__builtin_amdgcn_exp2f)
  return __builtin_amdgcn_exp2f(x);
#else
  float r; asm("v_exp_f32 %0, %1" : "=v"(r) : "v"(x)); return r;
#endif
}

static __device__ __forceinline__ void gload_lds16(const unsigned short* g, void* l){
  __builtin_amdgcn_global_load_lds((const __attribute__((address_space(1))) void*)g,
                                   (__attribute__((address_space(3))) void*)l,
                                   16, 0, 0);
}

// ---------------- fp32 -> bf16 conversion (x) ----------------
__global__ void cvt_bf16_kernel(const float* __restrict__ src,
                                unsigned short* __restrict__ dst, int n4){
  int i = blockIdx.x*blockDim.x + threadIdx.x;
  if (i >= n4) return;
  float4 f = ((const float4*)src)[i];
  short4v o;
  o.x = (short)f2b(f.x); o.y = (short)f2b(f.y);
  o.z = (short)f2b(f.z); o.w = (short)f2b(f.w);
  ((short4v*)dst)[i] = o;
}

// ---------------- weight conversion: wq|wk|wv -> wcat, wo -> wob ----------------
__global__ void cvt_w_kernel(const float* __restrict__ wq, const float* __restrict__ wk,
                             const float* __restrict__ wv, const float* __restrict__ wo,
                             unsigned short* __restrict__ wcat, unsigned short* __restrict__ wob){
  int i = blockIdx.x*blockDim.x + threadIdx.x;     // 4 * 262144 float4s
  int seg = i >> 18;
  int j = i & 0x3FFFF;
  const float* s = (seg==0) ? wq : (seg==1) ? wk : (seg==2) ? wv : wo;
  unsigned short* d = (seg < 3) ? (wcat + ((size_t)seg << 20)) : wob;
  float4 f = ((const float4*)s)[j];
  short4v o;
  o.x = (short)f2b(f.x); o.y = (short)f2b(f.y);
  o.z = (short)f2b(f.z); o.w = (short)f2b(f.w);
  ((short4v*)d)[j] = o;
}

// ---------------- RoPE cos/sin table: tab[s][j] = (cos, sin), j=0..31 ----------------
__global__ void rope_tab_kernel(const int* __restrict__ pos, float2* __restrict__ tab){
  int i = blockIdx.x*blockDim.x + threadIdx.x;
  if (i >= SEQ*32) return;
  int s = i >> 5, j = i & 31;
  float p = (float)pos[s];
  float fr = expf(-((float)(2*j) * (1.0f/DKH)) * 9.210340371976184f); // theta^(-2j/dk)
  float sn, cs;
  sincosf(p * fr, &sn, &cs);
  tab[i] = make_float2(cs, sn);
}

// ---------------- NT GEMM, m97-style: global_load_lds staging ----------------
// C = A(MxK) * Bw(NxK)^T
// MODE 0: N=3072 fused QKV. which = n0>>10 (uniform per block):
//   which<2  : apply RoPE (table) and scatter bf16 into Q/K[(b,h,s,d)]
//   which==2 : transpose 128x128 tile through LDS, write V^T[(b,h,d,s)]
// MODE 1: fp32 row-major MxN (output projection)
#define BM 128
#define BN 128
#define BKG 64

template<int MODE>
__global__ __launch_bounds__(256, 3) void gemm_nt(const unsigned short* __restrict__ A,
                                                  const unsigned short* __restrict__ Bw,
                                                  void* __restrict__ C,
                                                  const float2* __restrict__ tab,
                                                  int M, int N, int K)
{
  __shared__ unsigned short smem[BM*BKG + BN*BKG];   // As | Bs ; reused for V transpose
  unsigned short* As = smem;
  unsigned short* Bs = smem + BM*BKG;
  const int t = threadIdx.x;
  const int lane = t & 63;
  const int wv = t >> 6;
  const int wr = wv >> 1, wc = wv & 1;
  const int l15 = lane & 15, l4 = lane >> 4;
  const int m0 = blockIdx.y*BM, n0 = blockIdx.x*BN;

  f32x4 acc[4][4] = {};

  const int srow = lane >> 3;          // 0..7 within 8-row chunk
  const int sce  = (lane & 7) * 8;     // element offset in k within row

  for (int kt = 0; kt < K; kt += BKG){
    __syncthreads();
    #pragma unroll
    for (int jj = 0; jj < 4; ++jj){
      const int i = wv + jj*4;
      const int row = i*8 + srow;
      gload_lds16(A  + (size_t)(m0 + row)*K + kt + sce, (char*)As + i*1024 + lane*16);
      gload_lds16(Bw + (size_t)(n0 + row)*K + kt + sce, (char*)Bs + i*1024 + lane*16);
    }
    __syncthreads();
    #pragma unroll
    for (int kk = 0; kk < 2; ++kk){
      bf16x8 af[4], bfr[4];
      #pragma unroll
      for (int mi = 0; mi < 4; ++mi)
        af[mi] = *(const bf16x8*)((const char*)As + (wr*64 + mi*16 + l15)*128 + kk*64 + l4*16);
      #pragma unroll
      for (int ni = 0; ni < 4; ++ni)
        bfr[ni] = *(const bf16x8*)((const char*)Bs + (wc*64 + ni*16 + l15)*128 + kk*64 + l4*16);
      #pragma unroll
      for (int mi = 0; mi < 4; ++mi)
        #pragma unroll
        for (int ni = 0; ni < 4; ++ni)
          acc[mi][ni] = mfma16(af[mi], bfr[ni], acc[mi][ni]);
    }
  }

  if (MODE == 1){
    #pragma unroll
    for (int mi = 0; mi < 4; ++mi)
      #pragma unroll
      for (int ni = 0; ni < 4; ++ni)
        #pragma unroll
        for (int r = 0; r < 4; ++r){
          int row = m0 + wr*64 + mi*16 + l4*4 + r;
          int col = n0 + wc*64 + ni*16 + l15;
          ((float*)C)[(size_t)row*N + col] = acc[mi][ni][r];
        }
    return;
  }

  const int which = n0 >> 10;            // 0=Q 1=K 2=V (uniform per block)

  if (which == 2){
    // ---- V path: transpose 128x128 tile via LDS, write (bh, d, s) ----
    __syncthreads();   // done reading As/Bs
    #pragma unroll
    for (int mi = 0; mi < 4; ++mi)
      #pragma unroll
      for (int ni = 0; ni < 4; ++ni){
        int d_l = wc*64 + ni*16 + l15;            // 0..127 (2 heads)
        int s0  = wr*64 + mi*16 + l4*4;           // 0..124 step 4
        short4v pk;
        pk.x = (short)f2b(acc[mi][ni][0]);
        pk.y = (short)f2b(acc[mi][ni][1]);
        pk.z = (short)f2b(acc[mi][ni][2]);
        pk.w = (short)f2b(acc[mi][ni][3]);
        int byte = d_l*256 + ((s0*2) ^ ((d_l & 7) << 4));
        *(short4v*)((char*)smem + byte) = pk;
      }
    __syncthreads();
    const int d_l = t >> 1;                        // 0..127
    const int half = t & 1;                        // s half (64 each)
    const int hb = (n0 & 1023) >> 6;               // base head of this block pair
    const int b = m0 >> 11;
    const int s_b = m0 & (SEQ-1);                  // s offset WITHIN the batch
    const int bh = b*NHEADS + hb + (d_l >> 6);
    const int d = d_l & 63;
    unsigned short* vt = (unsigned short*)C + 2*((size_t)BH_*SEQ*DKH);
    unsigned short* dst = vt + ((size_t)bh*DKH + d)*SEQ + s_b + half*64;
    #pragma unroll
    for (int c = 0; c < 8; ++c){                   // 8 x 8 bf16 = full 64-s half (bugfix)
      int sl = half*64 + c*8;
      int byte = d_l*256 + ((sl*2) ^ ((d_l & 7) << 4));
      *(bf16x8*)(dst + c*8) = *(const bf16x8*)((const char*)smem + byte);
    }
    return;
  }

  // ---- Q/K path: RoPE via table, scatter to (b,h,s,d) ----
  unsigned short* qk = (unsigned short*)C + (size_t)which*((size_t)BH_*SEQ*DKH);
  #pragma unroll
  for (int ni = 0; ni < 4; ++ni){
    int col = n0 + wc*64 + ni*16 + l15;
    int cl = col & 1023;
    int h = cl >> 6, dd = cl & (DKH-1);
    int j = dd >> 1;
    bool odd = dd & 1;
    #pragma unroll
    for (int mi = 0; mi < 4; ++mi)
      #pragma unroll
      for (int r = 0; r < 4; ++r){
        int row = m0 + wr*64 + mi*16 + l4*4 + r;
        int b = row >> 11, s = row & (SEQ-1);
        float2 cst = tab[s*32 + j];
        float xv = acc[mi][ni][r];
        float pv = __shfl_xor(xv, 1);
        float res = odd ? fmaf(xv, cst.x,  pv*cst.y)
                        : fmaf(xv, cst.x, -pv*cst.y);
        qk[((size_t)(b*NHEADS + h)*SEQ + s)*DKH + dd] = f2b(res);
      }
  }
}

// ---------------- causal flash attention, 4 waves x 32 q-rows ----------------
#define QW 32
#define QB 128
#define KVB 64

__global__ __launch_bounds__(256, 3) void attn_kernel(const unsigned short* __restrict__ Q,
                                                      const unsigned short* __restrict__ Kw,
                                                      const unsigned short* __restrict__ Vt,
                                                      unsigned short* __restrict__ Ob)
{
  __shared__ unsigned short Ks[2][KVB*64];
  __shared__ unsigned short Vs[2][KVB*64];
  __shared__ unsigned short Ps[4][QW*KVB];

  const int t = threadIdx.x;
  const int lane = t & 63;
  const int wv = t >> 6;
  const int l15 = lane & 15, l4 = lane >> 4;

  const int bid = blockIdx.x;
  const int bh = bid & (BH_-1);
  const int qt = (SEQ/QB - 1) - (bid >> 6);
  const int q0 = qt * QB;
  const int qw0 = q0 + wv*QW;

  const unsigned short* kg = Kw + (size_t)bh*SEQ*DKH;
  const unsigned short* vg = Vt + (size_t)bh*DKH*SEQ;
  const unsigned short* qg = Q  + ((size_t)bh*SEQ + qw0)*DKH;

  bf16x8 qa[2][2];
  #pragma unroll
  for (int qi = 0; qi < 2; ++qi)
    #pragma unroll
    for (int c = 0; c < 2; ++c)
      qa[qi][c] = *(const bf16x8*)(qg + (qi*16 + l15)*DKH + c*32 + l4*8);

  const float KAPPA = 0.125f * 1.4426950408889634f;
  float m_r[2] = {-1e30f, -1e30f};
  float l_r[2] = {0.f, 0.f};
  f32x4 oacc[2][4] = {};

  const int srow = t >> 3;
  const int scb  = (t & 7) * 16;
  const int sko  = scb ^ ((srow & 7) << 4);
  const size_t vstride = (size_t)SEQ * 2;

  const int ntB   = q0/KVB + 2;
  const int twmax = (qw0 + QW - 1) >> 6;

  bf16x8 kl0, kl1, vl0, vl1;
  {
    const char* ksrc = (const char*)kg;
    const char* vsrc = (const char*)vg;
    kl0 = *(const bf16x8*)(ksrc + srow*128 + sko);
    kl1 = *(const bf16x8*)(ksrc + (srow+32)*128 + sko);
    vl0 = *(const bf16x8*)(vsrc + (size_t)srow*vstride + sko);
    vl1 = *(const bf16x8*)(vsrc + (size_t)(srow+32)*vstride + sko);
    *(bf16x8*)((char*)Ks[0] + srow*128 + scb)      = kl0;
    *(bf16x8*)((char*)Ks[0] + (srow+32)*128 + scb) = kl1;
    *(bf16x8*)((char*)Vs[0] + srow*128 + scb)      = vl0;
    *(bf16x8*)((char*)Vs[0] + (srow+32)*128 + scb) = vl1;
  }

  for (int tt = 0; tt < ntB; ++tt){
    const int cur = tt & 1;
    __syncthreads();
    const bool pre = (tt + 1 < ntB);
    if (pre){
      const size_t kvoff = (size_t)(tt+1) * KVB;
      const char* ksrc = (const char*)kg + kvoff*128;
      const char* vsrc = (const char*)vg + kvoff*2;
      kl0 = *(const bf16x8*)(ksrc + srow*128 + sko);
      kl1 = *(const bf16x8*)(ksrc + (srow+32)*128 + sko);
      vl0 = *(const bf16x8*)(vsrc + (size_t)srow*vstride + sko);
      vl1 = *(const bf16x8*)(vsrc + (size_t)(srow+32)*vstride + sko);
    }

    if (tt <= twmax){
      const char* kb = (const char*)Ks[cur];
      const char* vb = (const char*)Vs[cur];
      char* pb = (char*)Ps[wv];
      const int sw = (l15 & 7) << 4;
      const bool needmask = (tt == twmax);

      f32x4 sacc[4][2];
      #pragma unroll
      for (int kt = 0; kt < 4; ++kt){
        const int krow = kt*16 + l15;
        bf16x8 kf0 = *(const bf16x8*)(kb + krow*128 + ((l4*16) ^ sw));
        bf16x8 kf1 = *(const bf16x8*)(kb + krow*128 + ((64 + l4*16) ^ sw));
        #pragma unroll
        for (int qi = 0; qi < 2; ++qi){
          f32x4 a = {};
          a = mfma16(kf0, qa[qi][0], a);
          a = mfma16(kf1, qa[qi][1], a);
          sacc[kt][qi] = a;
        }
      }

      const int kv0 = tt * KVB;
      #pragma unroll
      for (int qi = 0; qi < 2; ++qi){
        const int qrow = qw0 + qi*16 + l15;
        float p[16];
        float mloc = -1e30f;
        #pragma unroll
        for (int kt = 0; kt < 4; ++kt)
          #pragma unroll
          for (int r = 0; r < 4; ++r){
            float x = sacc[kt][qi][r] * KAPPA;
            if (needmask){
              int kvg = kv0 + kt*16 + l4*4 + r;
              x = (kvg > qrow) ? -1e30f : x;
            }
            p[kt*4+r] = x;
            mloc = fmaxf(mloc, x);
          }
        mloc = fmaxf(mloc, __shfl_xor(mloc, 16));
        mloc = fmaxf(mloc, __shfl_xor(mloc, 32));

        const bool skip = __all(mloc - m_r[qi] <= 12.0f);
        float mn = m_r[qi];
        if (!skip){
          mn = fmaxf(m_r[qi], mloc);
          float alpha = fexp2(m_r[qi] - mn);
          m_r[qi] = mn;
          l_r[qi] *= alpha;
          float ar[4];
          #pragma unroll
          for (int r = 0; r < 4; ++r) ar[r] = __shfl(alpha, l4*4 + r);
          #pragma unroll
          for (int dt = 0; dt < 4; ++dt)
            #pragma unroll
            for (int r = 0; r < 4; ++r) oacc[qi][dt][r] *= ar[r];
        }
        float rs = 0.f;
        #pragma unroll
        for (int i = 0; i < 16; ++i){ p[i] = fexp2(p[i] - mn); rs += p[i]; }
        rs += __shfl_xor(rs, 16);
        rs += __shfl_xor(rs, 32);
        l_r[qi] += rs;

        char* pr = pb + (qi*16 + l15)*128;
        #pragma unroll
        for (int kt = 0; kt < 4; ++kt){
          unsigned u0, u1;
          asm("v_cvt_pk_bf16_f32 %0, %1, %2" : "=v"(u0) : "v"(p[kt*4+0]), "v"(p[kt*4+1]));
          asm("v_cvt_pk_bf16_f32 %0, %1, %2" : "=v"(u1) : "v"(p[kt*4+2]), "v"(p[kt*4+3]));
          unsigned long long uu = (unsigned long long)u0 | ((unsigned long long)u1 << 32);
          *(unsigned long long*)(pr + ((kt*32 + l4*8) ^ sw)) = uu;
        }
      }

      bf16x8 pa[2][2];
      #pragma unroll
      for (int qi = 0; qi < 2; ++qi){
        const char* pr = pb + (qi*16 + l15)*128;
        pa[qi][0] = *(const bf16x8*)(pr + ((l4*16) ^ sw));
        pa[qi][1] = *(const bf16x8*)(pr + ((64 + l4*16) ^ sw));
      }

      #pragma unroll
      for (int dt = 0; dt < 4; ++dt){
        const int vrow = dt*16 + l15;
        bf16x8 vf0 = *(const bf16x8*)(vb + vrow*128 + ((l4*16) ^ sw));
        bf16x8 vf1 = *(const bf16x8*)(vb + vrow*128 + ((64 + l4*16) ^ sw));
        #pragma unroll
        for (int qi = 0; qi < 2; ++qi){
          oacc[qi][dt] = mfma16(pa[qi][0], vf0, oacc[qi][dt]);
          oacc[qi][dt] = mfma16(pa[qi][1], vf1, oacc[qi][dt]);
        }
      }
    }

    if (pre){
      char* kd = (char*)Ks[cur^1];
      char* vd = (char*)Vs[cur^1];
      *(bf16x8*)(kd + srow*128 + scb)      = kl0;
      *(bf16x8*)(kd + (srow+32)*128 + scb) = kl1;
      *(bf16x8*)(vd + srow*128 + scb)      = vl0;
      *(bf16x8*)(vd + (srow+32)*128 + scb) = vl1;
    }
  }

  const int b = bh >> 4, h = bh & 15;
  #pragma unroll
  for (int qi = 0; qi < 2; ++qi){
    float inv = 1.0f / l_r[qi];
    float ir[4];
    #pragma unroll
    for (int r = 0; r < 4; ++r) ir[r] = __shfl(inv, l4*4 + r);
    #pragma unroll
    for (int r = 0; r < 4; ++r){
      int q = qw0 + qi*16 + l4*4 + r;
      unsigned short* orow = Ob + ((size_t)(b*SEQ + q))*D_MODEL + h*DKH;
      #pragma unroll
      for (int dt = 0; dt < 4; ++dt)
        orow[dt*16 + l15] = f2b(oacc[qi][dt][r] * ir[r]);
    }
  }
}

// ---------------- host orchestration ----------------
extern "C" void kernel_launch(void* const* d_in, const int* in_sizes, int n_in,
                              void* d_out, int out_size, void* d_ws, size_t ws_size,
                              hipStream_t stream)
{
  const float* x  = (const float*)d_in[0];
  const float* wq = (const float*)d_in[1];
  const float* wk = (const float*)d_in[2];
  const float* wv = (const float*)d_in[3];
  const float* wo = (const float*)d_in[4];
  const int* tp   = (const int*)d_in[5];
  float* out = (float*)d_out;

  unsigned short* ws = (unsigned short*)d_ws;
  size_t off = 0;
  unsigned short* xb   = ws + off; off += (size_t)MROWS*D_MODEL;
  unsigned short* wcat = ws + off; off += (size_t)3*D_MODEL*D_MODEL;
  unsigned short* wob  = ws + off; off += (size_t)D_MODEL*D_MODEL;
  unsigned short* qw   = ws + off; off += (size_t)BH_*SEQ*DKH;   // Q | K | V^T contiguous
  unsigned short* kw   = ws + off; off += (size_t)BH_*SEQ*DKH;
  unsigned short* vt   = ws + off; off += (size_t)BH_*SEQ*DKH;
  unsigned short* ao   = ws + off; off += (size_t)BH_*SEQ*DKH;
  float2* tab = (float2*)(ws + off); off += (size_t)SEQ*32*4;

  cvt_bf16_kernel<<<(MROWS*D_MODEL/4 + 255)/256, 256, 0, stream>>>(x, xb, MROWS*D_MODEL/4);
  cvt_w_kernel<<<(4*262144 + 255)/256, 256, 0, stream>>>(wq, wk, wv, wo, wcat, wob);
  rope_tab_kernel<<<(SEQ*32 + 255)/256, 256, 0, stream>>>(tp, tab);

  // fused QKV projection (+RoPE on Q/K, +V transpose), N = 3072
  gemm_nt<0><<<dim3(3*D_MODEL/BN, MROWS/BM), 256, 0, stream>>>(xb, wcat, qw, tab,
                                                               MROWS, 3*D_MODEL, D_MODEL);

  attn_kernel<<<BH_*(SEQ/QB), 256, 0, stream>>>(qw, kw, vt, ao);

  gemm_nt<1><<<dim3(D_MODEL/BN, MROWS/BM), 256, 0, stream>>>(ao, wob, out, nullptr,
                                                             MROWS, D_MODEL, D_MODEL);
}